// Round 1
// baseline (268.855 us; speedup 1.0000x reference)
//
#include <hip/hip_runtime.h>

typedef unsigned int u32;
typedef __bf16 bf16x8 __attribute__((ext_vector_type(8)));
typedef float f32x4 __attribute__((ext_vector_type(4)));

#define N_TOK 4096   // B*S
#define IN_DIM 2048
#define OUT_DIM 4096
#define NCB 128      // codebooks C
#define NCENT 16     // centroids K
#define VLEN 16      // vec_len V
#define CK 2048      // NCB*NCENT  (GEMM inner dim)

static __device__ __forceinline__ unsigned short f2bf(float f) {
  u32 u = __float_as_uint(f);
  u = (u + 0x7FFFu + ((u >> 16) & 1u)) >> 16;  // round-to-nearest-even
  return (unsigned short)u;
}

// ---------------------------------------------------------------------------
// Kernel 1: per (token, codebook) Chebyshev argmin -> one-hot bf16 row of A
// Block = 256 threads = 2 tokens x 128 codebooks. Must match numpy argmin
// exactly: fp32 sub/abs/max are exact-order-independent; strict < ascending k
// reproduces first-min tie-breaking.
// ---------------------------------------------------------------------------
__global__ void k_argmin_onehot(const float* __restrict__ x,
                                const float* __restrict__ cents,
                                unsigned short* __restrict__ A) {
  __shared__ float xs[2 * IN_DIM];
  const int tid = threadIdx.x;
  const int n0 = blockIdx.x * 2;
  const float4* xsrc = (const float4*)(x + (size_t)n0 * IN_DIM);
  float4* xdst = (float4*)xs;
#pragma unroll
  for (int i = 0; i < 4; ++i) xdst[tid + 256 * i] = xsrc[tid + 256 * i];
  __syncthreads();
  const int ln = tid >> 7;   // local token 0..1
  const int c  = tid & 127;  // codebook
  const float* xv = xs + ln * IN_DIM + c * VLEN;
  float xr[VLEN];
#pragma unroll
  for (int v = 0; v < VLEN; ++v) xr[v] = xv[v];
  const float* cb = cents + c * (NCENT * VLEN);
  int bk = 0;
  float bd = 1e30f;
#pragma unroll
  for (int k = 0; k < NCENT; ++k) {
    float d = 0.f;
#pragma unroll
    for (int v = 0; v < VLEN; ++v) d = fmaxf(d, fabsf(xr[v] - cb[k * VLEN + v]));
    if (d < bd) { bd = d; bk = k; }
  }
  u32 pk[8];
#pragma unroll
  for (int j = 0; j < 8; ++j) {
    u32 w = 0u;
    if ((bk >> 1) == j) w = 0x3F80u << ((bk & 1) * 16);  // bf16(1.0)
    pk[j] = w;
  }
  u32* dst = (u32*)(A + (size_t)(n0 + ln) * CK + c * NCENT);
  *(uint4*)dst       = make_uint4(pk[0], pk[1], pk[2], pk[3]);
  *(uint4*)(dst + 4) = make_uint4(pk[4], pk[5], pk[6], pk[7]);
}

// ---------------------------------------------------------------------------
// Kernel 2: lutT[o][c*16+k] = sum_v cents[c,k,v] * weight[c*16+v][o]  (bf16)
// Block = (codebook c, o-tile of 256). Weight reads fully coalesced; the
// 32B/thread output scatter is fine (16.8 MB total, ~5 us corner).
// ---------------------------------------------------------------------------
__global__ void k_lut(const float* __restrict__ w,
                      const float* __restrict__ cents,
                      unsigned short* __restrict__ lutT) {
  __shared__ float cs[NCENT * VLEN];
  const int c = blockIdx.x;
  const int tid = threadIdx.x;
  const int o = blockIdx.y * 256 + tid;
  cs[tid] = cents[c * (NCENT * VLEN) + tid];
  __syncthreads();
  float acc[NCENT];
#pragma unroll
  for (int k = 0; k < NCENT; ++k) acc[k] = 0.f;
#pragma unroll
  for (int v = 0; v < VLEN; ++v) {
    const float wv = w[(size_t)(c * VLEN + v) * OUT_DIM + o];
#pragma unroll
    for (int k = 0; k < NCENT; ++k) acc[k] = fmaf(cs[k * VLEN + v], wv, acc[k]);
  }
  u32 pk[8];
#pragma unroll
  for (int j = 0; j < 8; ++j)
    pk[j] = (u32)f2bf(acc[2 * j]) | ((u32)f2bf(acc[2 * j + 1]) << 16);
  u32* dst = (u32*)(lutT + (size_t)o * CK + c * NCENT);
  *(uint4*)dst       = make_uint4(pk[0], pk[1], pk[2], pk[3]);
  *(uint4*)(dst + 4) = make_uint4(pk[4], pk[5], pk[6], pk[7]);
}

// ---------------------------------------------------------------------------
// Kernel 3: out[n][o] = sum_ck A[n][ck] * lutT[o][ck] + bias[o]
// m97-recipe bf16 GEMM: 128x128 tile, BK=32, 4 waves in 2x2, each wave 4x4
// grid of 16x16x32 MFMAs; global->LDS staging via global_load_lds width 16.
// ---------------------------------------------------------------------------
#define GLD16(g, l)                                                        \
  __builtin_amdgcn_global_load_lds(                                        \
      (const __attribute__((address_space(1))) u32*)(const void*)(g),      \
      (__attribute__((address_space(3))) u32*)(void*)(l), 16, 0, 0)

__global__ __launch_bounds__(256) void k_gemm(
    const unsigned short* __restrict__ A,   // [N_TOK][CK] bf16 bits
    const unsigned short* __restrict__ Bt,  // [OUT_DIM][CK] bf16 bits
    const float* __restrict__ bias,
    float* __restrict__ out) {
  __shared__ unsigned short sA[128 * 32];  // 8KB, row stride 32 (no pad: GLD)
  __shared__ unsigned short sB[128 * 32];  // 8KB
  const int tid = threadIdx.x;
  const int wave = tid >> 6;
  const int lane = tid & 63;
  const int m0 = blockIdx.x * 128;
  const int n0 = blockIdx.y * 128;
  const int wm = (wave >> 1) * 64;
  const int wn = (wave & 1) * 64;

  // staging: wave w covers rows [w*32, w*32+32), two 16-row issues;
  // lane -> row = lane/4, 16B chunk = lane%4 (LDS dest = base + lane*16)
  const int srow = lane >> 2;
  const int scol = (lane & 3) * 8;
  const unsigned short* gA = A + (size_t)(m0 + wave * 32 + srow) * CK + scol;
  const unsigned short* gB = Bt + (size_t)(n0 + wave * 32 + srow) * CK + scol;
  unsigned short* lA = sA + (wave * 32) * 32;
  unsigned short* lB = sB + (wave * 32) * 32;

  const int fr = lane & 15;        // fragment row (m or n)
  const int fc = (lane >> 4) * 8;  // fragment k offset

  f32x4 acc[4][4] = {};

  for (int k0 = 0; k0 < CK; k0 += 32) {
    GLD16(gA, lA);
    GLD16(gA + 16 * CK, lA + 16 * 32);
    GLD16(gB, lB);
    GLD16(gB + 16 * CK, lB + 16 * 32);
    gA += 32;
    gB += 32;
    __syncthreads();  // drains vmcnt: staging visible to all waves
    bf16x8 af[4], bfr[4];
#pragma unroll
    for (int i = 0; i < 4; ++i)
      af[i] = *(const bf16x8*)(sA + (wm + i * 16 + fr) * 32 + fc);
#pragma unroll
    for (int j = 0; j < 4; ++j)
      bfr[j] = *(const bf16x8*)(sB + (wn + j * 16 + fr) * 32 + fc);
#pragma unroll
    for (int i = 0; i < 4; ++i)
#pragma unroll
      for (int j = 0; j < 4; ++j)
        acc[i][j] =
            __builtin_amdgcn_mfma_f32_16x16x32_bf16(af[i], bfr[j], acc[i][j], 0, 0, 0);
    __syncthreads();  // compute done before next overwrite
  }

  // epilogue: D layout col=lane&15, row=(lane>>4)*4+r  [m89-verified]
  const int col = lane & 15;
  const int rb = (lane >> 4) * 4;
  float bj[4];
#pragma unroll
  for (int j = 0; j < 4; ++j) bj[j] = bias[n0 + wn + j * 16 + col];
#pragma unroll
  for (int i = 0; i < 4; ++i) {
    const int gm = m0 + wm + i * 16 + rb;
#pragma unroll
    for (int j = 0; j < 4; ++j) {
      const int gn = n0 + wn + j * 16 + col;
      float* op = out + (size_t)gm * OUT_DIM + gn;
#pragma unroll
      for (int r = 0; r < 4; ++r) op[(size_t)r * OUT_DIM] = acc[i][j][r] + bj[j];
    }
  }
}

// ---------------------------------------------------------------------------
extern "C" void kernel_launch(void* const* d_in, const int* in_sizes, int n_in,
                              void* d_out, int out_size, void* d_ws, size_t ws_size,
                              hipStream_t stream) {
  (void)in_sizes; (void)n_in; (void)out_size; (void)ws_size;
  const float* x      = (const float*)d_in[0];
  const float* weight = (const float*)d_in[1];
  const float* cents  = (const float*)d_in[2];
  const float* bias   = (const float*)d_in[3];
  // d_in[4] = vec_len (16), hardcoded

  unsigned short* A    = (unsigned short*)d_ws;          // [4096][2048] bf16 = 16.8MB
  unsigned short* lutT = A + (size_t)N_TOK * CK;         // [4096][2048] bf16 = 16.8MB
  float* out = (float*)d_out;

  k_argmin_onehot<<<dim3(N_TOK / 2), 256, 0, stream>>>(x, cents, A);
  k_lut<<<dim3(NCB, OUT_DIM / 256), 256, 0, stream>>>(weight, cents, lutT);
  k_gemm<<<dim3(N_TOK / 128, OUT_DIM / 128), 256, 0, stream>>>(A, lutT, bias, out);
}

// Round 2
// 225.468 us; speedup vs baseline: 1.1924x; 1.1924x over previous
//
#include <hip/hip_runtime.h>

typedef unsigned int u32;
typedef __bf16 bf16x8 __attribute__((ext_vector_type(8)));
typedef float f32x4 __attribute__((ext_vector_type(4)));

#define N_TOK 4096   // B*S
#define IN_DIM 2048
#define OUT_DIM 4096
#define NCB 128      // codebooks C
#define NCENT 16     // centroids K
#define VLEN 16      // vec_len V
#define CK 2048      // NCB*NCENT  (GEMM inner dim)

static __device__ __forceinline__ unsigned short f2bf(float f) {
  u32 u = __float_as_uint(f);
  u = (u + 0x7FFFu + ((u >> 16) & 1u)) >> 16;  // round-to-nearest-even
  return (unsigned short)u;
}

// ---------------------------------------------------------------------------
// Kernel 1: per (token, codebook) Chebyshev argmin -> one-hot bf16 row of A
// Block = 256 tokens x ONE codebook (blockIdx.y). Centroid reads are
// wave-uniform -> scalar s_load (no vector-memory gather). Each thread reads
// its own 64B contiguous x sub-vector (full line utilization).
// Must match numpy argmin exactly: fp32 sub/abs/max, strict < ascending k.
// ---------------------------------------------------------------------------
__global__ __launch_bounds__(256) void k_argmin_onehot(
    const float* __restrict__ x,
    const float* __restrict__ cents,
    unsigned short* __restrict__ A) {
  const int n = blockIdx.x * 256 + threadIdx.x;
  const int c = blockIdx.y;  // uniform across block -> scalar loads below

  // x sub-vector: 64B contiguous per thread
  const float4* xp = (const float4*)(x + (size_t)n * IN_DIM + c * VLEN);
  float xr[VLEN];
#pragma unroll
  for (int q = 0; q < 4; ++q) {
    float4 t = xp[q];
    xr[q * 4 + 0] = t.x; xr[q * 4 + 1] = t.y;
    xr[q * 4 + 2] = t.z; xr[q * 4 + 3] = t.w;
  }

  const float* cb = cents + (size_t)c * (NCENT * VLEN);  // uniform base
  int bk = 0;
  float bd = 1e30f;
#pragma unroll
  for (int k = 0; k < NCENT; ++k) {
    float d = 0.f;
#pragma unroll
    for (int v = 0; v < VLEN; ++v) d = fmaxf(d, fabsf(xr[v] - cb[k * VLEN + v]));
    if (d < bd) { bd = d; bk = k; }  // strict <: first-min, matches np.argmin
  }

  u32 pk[8];
#pragma unroll
  for (int j = 0; j < 8; ++j) {
    u32 w = 0u;
    if ((bk >> 1) == j) w = 0x3F80u << ((bk & 1) * 16);  // bf16(1.0)
    pk[j] = w;
  }
  u32* dst = (u32*)(A + (size_t)n * CK + c * NCENT);
  *(uint4*)dst       = make_uint4(pk[0], pk[1], pk[2], pk[3]);
  *(uint4*)(dst + 4) = make_uint4(pk[4], pk[5], pk[6], pk[7]);
}

// ---------------------------------------------------------------------------
// Kernel 2: lutT[o][c*16+k] = sum_v cents[c,k,v] * weight[c*16+v][o]  (bf16)
// Block = (codebook c, o-tile of 256). Weight reads fully coalesced.
// ---------------------------------------------------------------------------
__global__ __launch_bounds__(256) void k_lut(const float* __restrict__ w,
                                             const float* __restrict__ cents,
                                             unsigned short* __restrict__ lutT) {
  __shared__ float cs[NCENT * VLEN];
  const int c = blockIdx.x;
  const int tid = threadIdx.x;
  const int o = blockIdx.y * 256 + tid;
  cs[tid] = cents[c * (NCENT * VLEN) + tid];
  __syncthreads();
  float acc[NCENT];
#pragma unroll
  for (int k = 0; k < NCENT; ++k) acc[k] = 0.f;
#pragma unroll
  for (int v = 0; v < VLEN; ++v) {
    const float wv = w[(size_t)(c * VLEN + v) * OUT_DIM + o];
#pragma unroll
    for (int k = 0; k < NCENT; ++k) acc[k] = fmaf(cs[k * VLEN + v], wv, acc[k]);
  }
  u32 pk[8];
#pragma unroll
  for (int j = 0; j < 8; ++j)
    pk[j] = (u32)f2bf(acc[2 * j]) | ((u32)f2bf(acc[2 * j + 1]) << 16);
  u32* dst = (u32*)(lutT + (size_t)o * CK + c * NCENT);
  *(uint4*)dst       = make_uint4(pk[0], pk[1], pk[2], pk[3]);
  *(uint4*)(dst + 4) = make_uint4(pk[4], pk[5], pk[6], pk[7]);
}

// ---------------------------------------------------------------------------
// Kernel 3: out[n][o] = sum_ck A[n][ck] * lutT[o][ck] + bias[o]
// m97-recipe bf16 GEMM: 128x128 tile, BK=32, 4 waves in 2x2, each wave 4x4
// grid of 16x16x32 MFMAs; global->LDS staging via global_load_lds width 16.
// ---------------------------------------------------------------------------
#define GLD16(g, l)                                                        \
  __builtin_amdgcn_global_load_lds(                                        \
      (const __attribute__((address_space(1))) u32*)(const void*)(g),      \
      (__attribute__((address_space(3))) u32*)(void*)(l), 16, 0, 0)

__global__ __launch_bounds__(256) void k_gemm(
    const unsigned short* __restrict__ A,   // [N_TOK][CK] bf16 bits
    const unsigned short* __restrict__ Bt,  // [OUT_DIM][CK] bf16 bits
    const float* __restrict__ bias,
    float* __restrict__ out) {
  __shared__ unsigned short sA[128 * 32];  // 8KB, row stride 32 (no pad: GLD)
  __shared__ unsigned short sB[128 * 32];  // 8KB
  const int tid = threadIdx.x;
  const int wave = tid >> 6;
  const int lane = tid & 63;
  const int m0 = blockIdx.x * 128;
  const int n0 = blockIdx.y * 128;
  const int wm = (wave >> 1) * 64;
  const int wn = (wave & 1) * 64;

  // staging: wave w covers rows [w*32, w*32+32), two 16-row issues;
  // lane -> row = lane/4, 16B chunk = lane%4 (LDS dest = base + lane*16)
  const int srow = lane >> 2;
  const int scol = (lane & 3) * 8;
  const unsigned short* gA = A + (size_t)(m0 + wave * 32 + srow) * CK + scol;
  const unsigned short* gB = Bt + (size_t)(n0 + wave * 32 + srow) * CK + scol;
  unsigned short* lA = sA + (wave * 32) * 32;
  unsigned short* lB = sB + (wave * 32) * 32;

  const int fr = lane & 15;        // fragment row (m or n)
  const int fc = (lane >> 4) * 8;  // fragment k offset

  f32x4 acc[4][4] = {};

  for (int k0 = 0; k0 < CK; k0 += 32) {
    GLD16(gA, lA);
    GLD16(gA + 16 * CK, lA + 16 * 32);
    GLD16(gB, lB);
    GLD16(gB + 16 * CK, lB + 16 * 32);
    gA += 32;
    gB += 32;
    __syncthreads();  // drains vmcnt: staging visible to all waves
    bf16x8 af[4], bfr[4];
#pragma unroll
    for (int i = 0; i < 4; ++i)
      af[i] = *(const bf16x8*)(sA + (wm + i * 16 + fr) * 32 + fc);
#pragma unroll
    for (int j = 0; j < 4; ++j)
      bfr[j] = *(const bf16x8*)(sB + (wn + j * 16 + fr) * 32 + fc);
#pragma unroll
    for (int i = 0; i < 4; ++i)
#pragma unroll
      for (int j = 0; j < 4; ++j)
        acc[i][j] =
            __builtin_amdgcn_mfma_f32_16x16x32_bf16(af[i], bfr[j], acc[i][j], 0, 0, 0);
    __syncthreads();  // compute done before next overwrite
  }

  // epilogue: D layout col=lane&15, row=(lane>>4)*4+r  [m89-verified]
  const int col = lane & 15;
  const int rb = (lane >> 4) * 4;
  float bj[4];
#pragma unroll
  for (int j = 0; j < 4; ++j) bj[j] = bias[n0 + wn + j * 16 + col];
#pragma unroll
  for (int i = 0; i < 4; ++i) {
    const int gm = m0 + wm + i * 16 + rb;
#pragma unroll
    for (int j = 0; j < 4; ++j) {
      const int gn = n0 + wn + j * 16 + col;
      float* op = out + (size_t)gm * OUT_DIM + gn;
#pragma unroll
      for (int r = 0; r < 4; ++r) op[(size_t)r * OUT_DIM] = acc[i][j][r] + bj[j];
    }
  }
}

// ---------------------------------------------------------------------------
extern "C" void kernel_launch(void* const* d_in, const int* in_sizes, int n_in,
                              void* d_out, int out_size, void* d_ws, size_t ws_size,
                              hipStream_t stream) {
  (void)in_sizes; (void)n_in; (void)out_size; (void)ws_size;
  const float* x      = (const float*)d_in[0];
  const float* weight = (const float*)d_in[1];
  const float* cents  = (const float*)d_in[2];
  const float* bias   = (const float*)d_in[3];
  // d_in[4] = vec_len (16), hardcoded

  unsigned short* A    = (unsigned short*)d_ws;          // [4096][2048] bf16 = 16.8MB
  unsigned short* lutT = A + (size_t)N_TOK * CK;         // [4096][2048] bf16 = 16.8MB
  float* out = (float*)d_out;

  k_argmin_onehot<<<dim3(N_TOK / 256, NCB), 256, 0, stream>>>(x, cents, A);
  k_lut<<<dim3(NCB, OUT_DIM / 256), 256, 0, stream>>>(weight, cents, lutT);
  k_gemm<<<dim3(N_TOK / 128, OUT_DIM / 128), 256, 0, stream>>>(A, lutT, bias, out);
}